// Round 7
// baseline (651.992 us; speedup 1.0000x reference)
//
#include <hip/hip_runtime.h>

#define NN 100000
#define NE 1600000
#define H  128
#define NG 512
#define NC 10
#define SCAN_B 98     // ceil(NN/1024) ; also = number of dst buckets (dst>>10)
#define NBUCK  98
#define CHUNK  4096   // edges per pass-A block

typedef _Float16 f16;
typedef __attribute__((ext_vector_type(8))) _Float16 f16x8;
typedef __attribute__((ext_vector_type(4))) _Float16 f16x4;
typedef __attribute__((ext_vector_type(4))) float    f32x4;

// ---------------------------------------------------------------- utilities
__device__ __forceinline__ int lower_bound_i(const int* __restrict__ a, int n, int val) {
    int lo = 0, hi = n;
    while (lo < hi) {
        int mid = (lo + hi) >> 1;
        if (a[mid] < val) lo = mid + 1; else hi = mid;
    }
    return lo;
}

// ---------------------------------------------------------------- degree histogram
__global__ __launch_bounds__(256) void deg_kernel(const int* __restrict__ dst,
                                                  int* __restrict__ deg) {
    int e = blockIdx.x * 256 + threadIdx.x;
    if (e < NE) atomicAdd(&deg[dst[e]], 1);
}

// ---------------------------------------------------------------- parallel scan (3 stages)
__global__ __launch_bounds__(256) void scan1_kernel(const int* __restrict__ deg,
                                                    int* __restrict__ psum) {
    int b = blockIdx.x, t = threadIdx.x;
    int i4 = b * 1024 + t * 4;
    int s = 0;
    if (i4 + 3 < NN) {
        int4 v = *(const int4*)&deg[i4];
        s = v.x + v.y + v.z + v.w;
    } else {
        for (int k = 0; k < 4; ++k) if (i4 + k < NN) s += deg[i4 + k];
    }
    #pragma unroll
    for (int d = 32; d; d >>= 1) s += __shfl_down(s, d, 64);
    __shared__ int ws[4];
    if ((t & 63) == 0) ws[t >> 6] = s;
    __syncthreads();
    if (t == 0) psum[b] = ws[0] + ws[1] + ws[2] + ws[3];
}

__global__ void scan2_kernel(const int* __restrict__ psum, int* __restrict__ poff,
                             int* __restrict__ offs, int* __restrict__ bcur) {
    if (threadIdx.x == 0) {
        int run = 0;
        for (int b = 0; b < SCAN_B; ++b) { poff[b] = run; bcur[b] = run; run += psum[b]; }
        poff[SCAN_B] = run;
        offs[NN] = run;
    }
}

__global__ __launch_bounds__(256) void scan3_kernel(const int* __restrict__ deg,
                                                    const int* __restrict__ poff,
                                                    int* __restrict__ offs,
                                                    float* __restrict__ dis) {
    int b = blockIdx.x, t = threadIdx.x;
    int lane = t & 63, wid = t >> 6;
    int i4 = b * 1024 + t * 4;
    int v[4]; int s = 0;
    #pragma unroll
    for (int k = 0; k < 4; ++k) { int i = i4 + k; v[k] = (i < NN) ? deg[i] : 0; s += v[k]; }
    int incl = s;
    #pragma unroll
    for (int d = 1; d < 64; d <<= 1) { int u = __shfl_up(incl, d, 64); if (lane >= d) incl += u; }
    __shared__ int ws[4];
    if (lane == 63) ws[wid] = incl;
    __syncthreads();
    int wbase = 0;
    for (int w = 0; w < wid; ++w) wbase += ws[w];
    int base = poff[b] + wbase + incl - s;
    #pragma unroll
    for (int k = 0; k < 4; ++k) {
        int i = i4 + k;
        if (i < NN) {
            offs[i] = base;
            dis[i] = rsqrtf((float)v[k] + 1.0f);
        }
        base += v[k];
    }
}

// ---------------------------------------------------------------- pass A: bin edges by coarse bucket (dst>>10)
__global__ __launch_bounds__(256) void binA_kernel(const int* __restrict__ src,
                                                   const int* __restrict__ dst,
                                                   const float* __restrict__ dis,
                                                   int* __restrict__ bcur,
                                                   int2* __restrict__ binned) {
    __shared__ int  hist[NBUCK];
    __shared__ int  lbase[NBUCK];
    __shared__ int  gbase[NBUCK];
    __shared__ int  cur[NBUCK];
    __shared__ int2 stage[CHUNK];
    __shared__ int  destp[CHUNK];
    int t  = threadIdx.x;
    int e0 = blockIdx.x * CHUNK;
    int cnt = NE - e0; if (cnt > CHUNK) cnt = CHUNK;

    if (t < NBUCK) hist[t] = 0;
    __syncthreads();

    int s_[16], d_[16];
    #pragma unroll
    for (int i = 0; i < 16; ++i) {
        int e = e0 + i * 256 + t;
        if (e < NE) {
            s_[i] = src[e]; d_[i] = dst[e];
            atomicAdd(&hist[d_[i] >> 10], 1);
        } else { s_[i] = -1; d_[i] = 0; }
    }
    __syncthreads();

    if (t < NBUCK) {
        int lb = 0;
        for (int i = 0; i < t; ++i) lb += hist[i];
        lbase[t] = lb;
        cur[t]   = lb;
        gbase[t] = atomicAdd(&bcur[t], hist[t]);
    }
    __syncthreads();

    #pragma unroll
    for (int i = 0; i < 16; ++i) {
        if (s_[i] >= 0) {
            int s = s_[i], d = d_[i];
            int b = d >> 10;
            int r = atomicAdd(&cur[b], 1);
            float c = dis[s] * dis[d];
            stage[r] = make_int2(s | ((d & 1023) << 17), __float_as_int(c));
            destp[r] = gbase[b] + (r - lbase[b]);
        }
    }
    __syncthreads();

    #pragma unroll
    for (int i = 0; i < 16; ++i) {
        int idx = i * 256 + t;
        if (idx < cnt) binned[destp[idx]] = stage[idx];
    }
}

// ---------------------------------------------------------------- pass B: exact CSR placement within each bucket
__global__ __launch_bounds__(256) void binB_kernel(const int2* __restrict__ binned,
                                                   const int* __restrict__ poff,
                                                   const int* __restrict__ offs,
                                                   int2* __restrict__ edata) {
    __shared__ int cnt1k[1024];
    int b = blockIdx.x, t = threadIdx.x;
    #pragma unroll
    for (int i = 0; i < 4; ++i) cnt1k[t + i * 256] = 0;
    __syncthreads();
    int lo = poff[b], hi = poff[b + 1];
    for (int e = lo + t; e < hi; e += 256) {
        int2 p = binned[e];
        int dloc = (p.x >> 17) & 1023;
        int r = atomicAdd(&cnt1k[dloc], 1);
        int d = (b << 10) + dloc;
        edata[offs[d] + r] = p;
    }
}

// ---------------------------------------------------------------- W split prep: Wt_hi/Wt_lo [4][128][128] fp16, transposed
__global__ __launch_bounds__(256) void wprep_kernel(const float* __restrict__ W0,
                                                    const float* __restrict__ Ws,
                                                    f16* __restrict__ wt_hi,
                                                    f16* __restrict__ wt_lo) {
    int idx = blockIdx.x * 256 + threadIdx.x;   // 4*16384 total
    int m = idx >> 14;
    int k = (idx >> 7) & 127;
    int n = idx & 127;
    const float* Wm = (m == 0) ? W0 : (Ws + (size_t)(m - 1) * H * H);
    float v = Wm[k * H + n];
    f16 hi = (f16)v;
    float lo = v - (float)hi;
    wt_hi[(size_t)m * H * H + n * H + k] = hi;
    wt_lo[(size_t)m * H * H + n * H + k] = (f16)lo;
}

// ---------------------------------------------------------------- MFMA GEMM (LDS-free): hw = fp16((in0 [+ in1]) @ (W_hi + W_lo))
// 256 threads = 4 waves; wave w owns 32 rows (2 row-tiles of 16). 128 rows/block.
// A frags from global (4-lane lq-groups read 64B runs); W frags from global (L1/L2-hot).
// Swapped operands mfma(bF, aF): D lane = node (lane&15), regs = 4 consecutive W-cols
//   -> direct f16x4 (8B) stores, no LDS bounce, zero __syncthreads.
template <int FP32IN>
__global__ __launch_bounds__(256) void gemm_kernel(const void* __restrict__ in0,
                                                   const f16* __restrict__ in1,
                                                   const f16* __restrict__ wt_hi,
                                                   const f16* __restrict__ wt_lo,
                                                   f16* __restrict__ hw) {
    int t = threadIdx.x;
    int l = t & 63, w = t >> 6;
    int lr = l & 15, lq = l >> 4;
    int rowb = blockIdx.x * 128 + w * 32;

    f16x8 aF[2][4];
    #pragma unroll
    for (int rt = 0; rt < 2; ++rt) {
        int grow = rowb + rt * 16 + lr;
        if (grow >= NN) grow = NN - 1;
        #pragma unroll
        for (int ks = 0; ks < 4; ++ks) {
            int c = ks * 4 + lq;                 // k-chunk (16B) index 0..15
            f16x8 v;
            if (FP32IN) {
                const float* xp = (const float*)in0 + (size_t)grow * H + c * 8;
                f32x4 u0 = *(const f32x4*)xp;
                f32x4 u1 = *(const f32x4*)(xp + 4);
                #pragma unroll
                for (int u = 0; u < 4; ++u) { v[u] = (f16)u0[u]; v[u + 4] = (f16)u1[u]; }
            } else {
                v = *((const f16x8*)in0 + (size_t)grow * 16 + c);
                if (in1) {
                    f16x8 uu = *((const f16x8*)in1 + (size_t)grow * 16 + c);
                    v = v + uu;
                }
            }
            aF[rt][ks] = v;
        }
    }

    f32x4 acc[2][8];
    #pragma unroll
    for (int rt = 0; rt < 2; ++rt)
        #pragma unroll
        for (int ct = 0; ct < 8; ++ct)
            acc[rt][ct] = (f32x4){0.f, 0.f, 0.f, 0.f};

    const f16x8* wh = (const f16x8*)wt_hi;   // chunk layout: [n][c] = n*16 + c
    const f16x8* wl = (const f16x8*)wt_lo;
    #pragma unroll
    for (int p = 0; p < 2; ++p) {
        const f16x8* wp = p ? wl : wh;
        #pragma unroll
        for (int ks = 0; ks < 4; ++ks) {
            int c = ks * 4 + lq;
            #pragma unroll
            for (int ct = 0; ct < 8; ++ct) {
                int n = ct * 16 + lr;
                f16x8 bF = wp[n * 16 + c];
                acc[0][ct] = __builtin_amdgcn_mfma_f32_16x16x32_f16(bF, aF[0][ks], acc[0][ct], 0, 0, 0);
                acc[1][ct] = __builtin_amdgcn_mfma_f32_16x16x32_f16(bF, aF[1][ks], acc[1][ct], 0, 0, 0);
            }
        }
    }

    // store: node = lane&15 of each tile; 4 regs = W-cols ct*16 + lq*4 .. +3
    #pragma unroll
    for (int rt = 0; rt < 2; ++rt) {
        int grow = rowb + rt * 16 + lr;
        if (grow < NN) {
            #pragma unroll
            for (int ct = 0; ct < 8; ++ct) {
                f16x4 o;
                #pragma unroll
                for (int r = 0; r < 4; ++r) o[r] = (f16)acc[rt][ct][r];
                *(f16x4*)&hw[(size_t)grow * H + ct * 16 + lq * 4] = o;
            }
        }
    }
}

// ---------------------------------------------------------------- aggregation (fp16 out)
// one wave per node; quarter q owns edges k0+q and k0+4+q -> 8 edges in flight per wave
__global__ __launch_bounds__(256) void agg_kernel(const f16* __restrict__ hw,
                                                  const float* __restrict__ dis,
                                                  const int* __restrict__ offs,
                                                  const int2* __restrict__ edata,
                                                  const float* __restrict__ bias,
                                                  f16* __restrict__ outh) {
    int wid  = threadIdx.x >> 6;
    int lane = threadIdx.x & 63;
    int node = blockIdx.x * 4 + wid;
    if (node >= NN) return;
    int q  = lane >> 4;
    int j8 = (lane & 15) * 8;
    int beg = offs[node], end = offs[node + 1];
    int nk = end - beg;
    float acc[8];
    #pragma unroll
    for (int u = 0; u < 8; ++u) acc[u] = 0.f;

    for (int k0 = 0; k0 < nk; k0 += 8) {
        int kA = k0 + q, kB = k0 + 4 + q;
        int sa = 0; float ca = 0.f;
        int sb = 0; float cb = 0.f;
        if (kA < nk) {
            int2 e = edata[beg + kA];
            sa = e.x & 0x1FFFF; ca = __int_as_float(e.y);
        }
        if (kB < nk) {
            int2 e = edata[beg + kB];
            sb = e.x & 0x1FFFF; cb = __int_as_float(e.y);
        }
        f16x8 va = *(const f16x8*)&hw[(size_t)sa * H + j8];
        f16x8 vb = *(const f16x8*)&hw[(size_t)sb * H + j8];
        #pragma unroll
        for (int u = 0; u < 8; ++u) acc[u] += ca * (float)va[u];
        #pragma unroll
        for (int u = 0; u < 8; ++u) acc[u] += cb * (float)vb[u];
    }
    float dv = dis[node];
    f16x8 hv = *(const f16x8*)&hw[(size_t)node * H + j8];
    if (q == 0) {
        float sc = dv * dv;
        #pragma unroll
        for (int u = 0; u < 8; ++u) acc[u] += sc * (float)hv[u];
    }
    #pragma unroll
    for (int u = 0; u < 8; ++u) {
        acc[u] += __shfl_xor(acc[u], 16, 64);
        acc[u] += __shfl_xor(acc[u], 32, 64);
    }
    if (q == 0) {
        f16x8 o;
        #pragma unroll
        for (int u = 0; u < 8; ++u) o[u] = (f16)fmaxf(acc[u] + bias[j8 + u], 0.f);
        *(f16x8*)&outh[(size_t)node * H + j8] = o;
    }
}

// ---------------------------------------------------------------- mean-pool + linear head (2-way node-parallel)
__global__ __launch_bounds__(256) void pool_kernel(const f16* __restrict__ h,
                                                   const int* __restrict__ batch,
                                                   const float* __restrict__ linW,
                                                   const float* __restrict__ linb,
                                                   float* __restrict__ out) {
    __shared__ float pld[2][H];
    int g = blockIdx.x;
    int t = threadIdx.x;
    int f = t & 127, half = t >> 7;
    int lo = lower_bound_i(batch, NN, g);
    int hi = lower_bound_i(batch, NN, g + 1);
    float sum = 0.f;
    for (int n = lo + half; n < hi; n += 2) sum += (float)h[(size_t)n * H + f];
    pld[half][f] = sum;
    __syncthreads();
    if (t < H) {
        float cnt = (float)(hi - lo);
        pld[0][t] = (pld[0][t] + pld[1][t]) / fmaxf(cnt, 1.0f);
    }
    __syncthreads();
    if (t < NC) {
        float acc = linb[t];
        #pragma unroll 4
        for (int j = 0; j < H; ++j) acc += pld[0][j] * linW[j * NC + t];
        out[g * NC + t] = acc;
    }
}

// ---------------------------------------------------------------- launch
extern "C" void kernel_launch(void* const* d_in, const int* in_sizes, int n_in,
                              void* d_out, int out_size, void* d_ws, size_t ws_size,
                              hipStream_t stream) {
    const float* x     = (const float*)d_in[0];
    const int*   ei    = (const int*)d_in[1];
    const int*   batch = (const int*)d_in[2];
    const float* W0    = (const float*)d_in[3];
    const float* b0    = (const float*)d_in[4];
    const float* Ws    = (const float*)d_in[5];
    const float* bs    = (const float*)d_in[6];
    const float* linW  = (const float*)d_in[7];
    const float* linb  = (const float*)d_in[8];
    const int* src = ei;
    const int* dst = ei + NE;

    char* p = (char*)d_ws;
    auto alloc = [&](size_t bytes) -> void* {
        void* r = (void*)p;
        p += (bytes + 255) & ~(size_t)255;
        return r;
    };
    f16*   buf0   = (f16*)alloc((size_t)NN * H * 2);
    f16*   buf1   = (f16*)alloc((size_t)NN * H * 2);
    f16*   buf2   = (f16*)alloc((size_t)NN * H * 2);
    f16*   hwb    = (f16*)alloc((size_t)NN * H * 2);
    f16*   wt_hi  = (f16*)alloc((size_t)4 * H * H * 2);
    f16*   wt_lo  = (f16*)alloc((size_t)4 * H * H * 2);
    float* dis    = (float*)alloc((size_t)NN * 4);
    int*   deg    = (int*)alloc((size_t)NN * 4);
    int*   offs   = (int*)alloc((size_t)(NN + 1) * 4);
    int2*  binned = (int2*)alloc((size_t)NE * 8);
    int2*  edata  = (int2*)alloc((size_t)NE * 8);
    int*   psum   = (int*)alloc((size_t)SCAN_B * 4);
    int*   poff   = (int*)alloc((size_t)(SCAN_B + 1) * 4);
    int*   bcur   = (int*)alloc((size_t)NBUCK * 4);

    hipMemsetAsync(deg, 0, (size_t)NN * 4, stream);

    deg_kernel<<<(NE + 255) / 256, 256, 0, stream>>>(dst, deg);
    wprep_kernel<<<(4 * H * H) / 256, 256, 0, stream>>>(W0, Ws, wt_hi, wt_lo);
    scan1_kernel<<<SCAN_B, 256, 0, stream>>>(deg, psum);
    scan2_kernel<<<1, 64, 0, stream>>>(psum, poff, offs, bcur);
    scan3_kernel<<<SCAN_B, 256, 0, stream>>>(deg, poff, offs, dis);
    binA_kernel<<<(NE + CHUNK - 1) / CHUNK, 256, 0, stream>>>(src, dst, dis, bcur, binned);
    binB_kernel<<<NBUCK, 256, 0, stream>>>(binned, poff, offs, edata);

    int gemm_grid = (NN + 127) / 128;
    int agg_grid  = (NN + 3) / 4;
    size_t WSZ = (size_t)H * H;

    gemm_kernel<1><<<gemm_grid, 256, 0, stream>>>(x, nullptr, wt_hi, wt_lo, hwb);
    agg_kernel<<<agg_grid, 256, 0, stream>>>(hwb, dis, offs, edata, b0, buf0);
    gemm_kernel<0><<<gemm_grid, 256, 0, stream>>>(buf0, nullptr, wt_hi + WSZ, wt_lo + WSZ, hwb);
    agg_kernel<<<agg_grid, 256, 0, stream>>>(hwb, dis, offs, edata, bs, buf1);
    gemm_kernel<0><<<gemm_grid, 256, 0, stream>>>(buf1, buf0, wt_hi + 2 * WSZ, wt_lo + 2 * WSZ, hwb);
    agg_kernel<<<agg_grid, 256, 0, stream>>>(hwb, dis, offs, edata, bs + H, buf2);
    gemm_kernel<0><<<gemm_grid, 256, 0, stream>>>(buf2, buf1, wt_hi + 3 * WSZ, wt_lo + 3 * WSZ, hwb);
    agg_kernel<<<agg_grid, 256, 0, stream>>>(hwb, dis, offs, edata, bs + 2 * H, buf0);

    pool_kernel<<<NG, 256, 0, stream>>>(buf0, batch, linW, linb, (float*)d_out);
}

// Round 8
// 535.744 us; speedup vs baseline: 1.2170x; 1.2170x over previous
//
#include <hip/hip_runtime.h>

#define NN 100000
#define NE 1600000
#define H  128
#define NG 512
#define NC 10
#define SCAN_B 98     // ceil(NN/1024) ; also = number of dst buckets (dst>>10)
#define NBUCK  98
#define CHUNK  4096   // edges per pass-A block

typedef _Float16 f16;
typedef __attribute__((ext_vector_type(8))) _Float16 f16x8;
typedef __attribute__((ext_vector_type(4))) _Float16 f16x4;
typedef __attribute__((ext_vector_type(4))) float    f32x4;

// ---------------------------------------------------------------- utilities
__device__ __forceinline__ int lower_bound_i(const int* __restrict__ a, int n, int val) {
    int lo = 0, hi = n;
    while (lo < hi) {
        int mid = (lo + hi) >> 1;
        if (a[mid] < val) lo = mid + 1; else hi = mid;
    }
    return lo;
}

// ---------------------------------------------------------------- degree histogram
__global__ __launch_bounds__(256) void deg_kernel(const int* __restrict__ dst,
                                                  int* __restrict__ deg) {
    int e = blockIdx.x * 256 + threadIdx.x;
    if (e < NE) atomicAdd(&deg[dst[e]], 1);
}

// ---------------------------------------------------------------- parallel scan (3 stages)
__global__ __launch_bounds__(256) void scan1_kernel(const int* __restrict__ deg,
                                                    int* __restrict__ psum) {
    int b = blockIdx.x, t = threadIdx.x;
    int i4 = b * 1024 + t * 4;
    int s = 0;
    if (i4 + 3 < NN) {
        int4 v = *(const int4*)&deg[i4];
        s = v.x + v.y + v.z + v.w;
    } else {
        for (int k = 0; k < 4; ++k) if (i4 + k < NN) s += deg[i4 + k];
    }
    #pragma unroll
    for (int d = 32; d; d >>= 1) s += __shfl_down(s, d, 64);
    __shared__ int ws[4];
    if ((t & 63) == 0) ws[t >> 6] = s;
    __syncthreads();
    if (t == 0) psum[b] = ws[0] + ws[1] + ws[2] + ws[3];
}

__global__ void scan2_kernel(const int* __restrict__ psum, int* __restrict__ poff,
                             int* __restrict__ offs, int* __restrict__ bcur) {
    if (threadIdx.x == 0) {
        int run = 0;
        for (int b = 0; b < SCAN_B; ++b) { poff[b] = run; bcur[b] = run; run += psum[b]; }
        poff[SCAN_B] = run;
        offs[NN] = run;
    }
}

__global__ __launch_bounds__(256) void scan3_kernel(const int* __restrict__ deg,
                                                    const int* __restrict__ poff,
                                                    int* __restrict__ offs,
                                                    float* __restrict__ dis) {
    int b = blockIdx.x, t = threadIdx.x;
    int lane = t & 63, wid = t >> 6;
    int i4 = b * 1024 + t * 4;
    int v[4]; int s = 0;
    #pragma unroll
    for (int k = 0; k < 4; ++k) { int i = i4 + k; v[k] = (i < NN) ? deg[i] : 0; s += v[k]; }
    int incl = s;
    #pragma unroll
    for (int d = 1; d < 64; d <<= 1) { int u = __shfl_up(incl, d, 64); if (lane >= d) incl += u; }
    __shared__ int ws[4];
    if (lane == 63) ws[wid] = incl;
    __syncthreads();
    int wbase = 0;
    for (int w = 0; w < wid; ++w) wbase += ws[w];
    int base = poff[b] + wbase + incl - s;
    #pragma unroll
    for (int k = 0; k < 4; ++k) {
        int i = i4 + k;
        if (i < NN) {
            offs[i] = base;
            dis[i] = rsqrtf((float)v[k] + 1.0f);
        }
        base += v[k];
    }
}

// ---------------------------------------------------------------- pass A: bin edges by coarse bucket (dst>>10)
// payload int: src (17b) | dstloc (10b) << 17  — NO per-edge coefficient needed anymore
__global__ __launch_bounds__(256) void binA_kernel(const int* __restrict__ src,
                                                   const int* __restrict__ dst,
                                                   int* __restrict__ bcur,
                                                   int* __restrict__ binned) {
    __shared__ int hist[NBUCK];
    __shared__ int lbase[NBUCK];
    __shared__ int gbase[NBUCK];
    __shared__ int cur[NBUCK];
    __shared__ int stage[CHUNK];
    __shared__ int destp[CHUNK];
    int t  = threadIdx.x;
    int e0 = blockIdx.x * CHUNK;
    int cnt = NE - e0; if (cnt > CHUNK) cnt = CHUNK;

    if (t < NBUCK) hist[t] = 0;
    __syncthreads();

    int s_[16], d_[16];
    #pragma unroll
    for (int i = 0; i < 16; ++i) {
        int e = e0 + i * 256 + t;
        if (e < NE) {
            s_[i] = src[e]; d_[i] = dst[e];
            atomicAdd(&hist[d_[i] >> 10], 1);
        } else { s_[i] = -1; d_[i] = 0; }
    }
    __syncthreads();

    if (t < NBUCK) {
        int lb = 0;
        for (int i = 0; i < t; ++i) lb += hist[i];
        lbase[t] = lb;
        cur[t]   = lb;
        gbase[t] = atomicAdd(&bcur[t], hist[t]);
    }
    __syncthreads();

    #pragma unroll
    for (int i = 0; i < 16; ++i) {
        if (s_[i] >= 0) {
            int s = s_[i], d = d_[i];
            int b = d >> 10;
            int r = atomicAdd(&cur[b], 1);
            stage[r] = s | ((d & 1023) << 17);
            destp[r] = gbase[b] + (r - lbase[b]);
        }
    }
    __syncthreads();

    #pragma unroll
    for (int i = 0; i < 16; ++i) {
        int idx = i * 256 + t;
        if (idx < cnt) binned[destp[idx]] = stage[idx];
    }
}

// ---------------------------------------------------------------- pass B: exact CSR placement within each bucket
__global__ __launch_bounds__(256) void binB_kernel(const int* __restrict__ binned,
                                                   const int* __restrict__ poff,
                                                   const int* __restrict__ offs,
                                                   int* __restrict__ edata) {
    __shared__ int cnt1k[1024];
    int b = blockIdx.x, t = threadIdx.x;
    #pragma unroll
    for (int i = 0; i < 4; ++i) cnt1k[t + i * 256] = 0;
    __syncthreads();
    int lo = poff[b], hi = poff[b + 1];
    for (int e = lo + t; e < hi; e += 256) {
        int p = binned[e];
        int dloc = (p >> 17) & 1023;
        int r = atomicAdd(&cnt1k[dloc], 1);
        int d = (b << 10) + dloc;
        edata[offs[d] + r] = p & 0x1FFFF;    // store src only
    }
}

// ---------------------------------------------------------------- W split prep: Wt_hi/Wt_lo [4][128][128] fp16, transposed
__global__ __launch_bounds__(256) void wprep_kernel(const float* __restrict__ W0,
                                                    const float* __restrict__ Ws,
                                                    f16* __restrict__ wt_hi,
                                                    f16* __restrict__ wt_lo) {
    int idx = blockIdx.x * 256 + threadIdx.x;   // 4*16384 total
    int m = idx >> 14;
    int k = (idx >> 7) & 127;
    int n = idx & 127;
    const float* Wm = (m == 0) ? W0 : (Ws + (size_t)(m - 1) * H * H);
    float v = Wm[k * H + n];
    f16 hi = (f16)v;
    float lo = v - (float)hi;
    wt_hi[(size_t)m * H * H + n * H + k] = hi;
    wt_lo[(size_t)m * H * H + n * H + k] = (f16)lo;
}

// ---------------------------------------------------------------- MFMA GEMM: hw' = fp16(dis * ((in0 [+ in1]) @ (W_hi + W_lo)))
// 512 threads = 8 waves; wave owns 32 rows; 256 rows/block. W staged in 64KB LDS
// (swizzled, 2-way max conflict); A frags direct from global; swapped-operand MFMA
// -> D lane = node row, regs = 4 consecutive W-cols -> direct 8B stores. One sync.
template <int FP32IN>
__global__ __launch_bounds__(512) void gemm_kernel(const void* __restrict__ in0,
                                                   const f16* __restrict__ in1,
                                                   const f16* __restrict__ wt_hi,
                                                   const f16* __restrict__ wt_lo,
                                                   const float* __restrict__ dis,
                                                   f16* __restrict__ hw) {
    __shared__ f16x8 sW[2][128 * 16];   // 64 KB, chunk-swizzled (c ^ (n&7))
    int t = threadIdx.x;
    int l = t & 63, w = t >> 6;
    int lr = l & 15, lq = l >> 4;
    int rowb = blockIdx.x * 256 + w * 32;

    const f16x8* wh = (const f16x8*)wt_hi;
    const f16x8* wl = (const f16x8*)wt_lo;
    #pragma unroll
    for (int i = 0; i < 4; ++i) {
        int ch = i * 512 + t;           // 0..2047
        int n = ch >> 4, c = ch & 15;
        int sw = n * 16 + (c ^ (n & 7));
        sW[0][sw] = wh[ch];
        sW[1][sw] = wl[ch];
    }

    f16x8 aF[2][4];
    #pragma unroll
    for (int rt = 0; rt < 2; ++rt) {
        int grow = rowb + rt * 16 + lr;
        if (grow >= NN) grow = NN - 1;
        #pragma unroll
        for (int ks = 0; ks < 4; ++ks) {
            int c = ks * 4 + lq;                 // k-chunk (16B) index 0..15
            f16x8 v;
            if (FP32IN) {
                const float* xp = (const float*)in0 + (size_t)grow * H + c * 8;
                f32x4 u0 = *(const f32x4*)xp;
                f32x4 u1 = *(const f32x4*)(xp + 4);
                #pragma unroll
                for (int u = 0; u < 4; ++u) { v[u] = (f16)u0[u]; v[u + 4] = (f16)u1[u]; }
            } else {
                v = *((const f16x8*)in0 + (size_t)grow * 16 + c);
                if (in1) {
                    f16x8 uu = *((const f16x8*)in1 + (size_t)grow * 16 + c);
                    v = v + uu;
                }
            }
            aF[rt][ks] = v;
        }
    }
    __syncthreads();

    f32x4 acc[2][8];
    #pragma unroll
    for (int rt = 0; rt < 2; ++rt)
        #pragma unroll
        for (int ct = 0; ct < 8; ++ct)
            acc[rt][ct] = (f32x4){0.f, 0.f, 0.f, 0.f};

    #pragma unroll
    for (int p = 0; p < 2; ++p) {
        #pragma unroll
        for (int ks = 0; ks < 4; ++ks) {
            int c = ks * 4 + lq;
            #pragma unroll
            for (int ct = 0; ct < 8; ++ct) {
                int n = ct * 16 + lr;
                f16x8 bF = sW[p][n * 16 + (c ^ (n & 7))];
                acc[0][ct] = __builtin_amdgcn_mfma_f32_16x16x32_f16(bF, aF[0][ks], acc[0][ct], 0, 0, 0);
                acc[1][ct] = __builtin_amdgcn_mfma_f32_16x16x32_f16(bF, aF[1][ks], acc[1][ct], 0, 0, 0);
            }
        }
    }

    // store hw' = dis * result: node = lane&15 of each tile; 4 regs = W-cols ct*16+lq*4..+3
    #pragma unroll
    for (int rt = 0; rt < 2; ++rt) {
        int grow = rowb + rt * 16 + lr;
        if (grow < NN) {
            float dv = dis[grow];
            #pragma unroll
            for (int ct = 0; ct < 8; ++ct) {
                f16x4 o;
                #pragma unroll
                for (int r = 0; r < 4; ++r) o[r] = (f16)(dv * acc[rt][ct][r]);
                *(f16x4*)&hw[(size_t)grow * H + ct * 16 + lq * 4] = o;
            }
        }
    }
}

// ---------------------------------------------------------------- aggregation (fp16 out)
// out[d] = relu(dis[d] * (sum_e hw'[src_e] + hw'[d]) + bias)
// one wave per node; quarter q owns edges k0+q and k0+4+q -> 8 edges in flight per wave
__global__ __launch_bounds__(256) void agg_kernel(const f16* __restrict__ hw,
                                                  const float* __restrict__ dis,
                                                  const int* __restrict__ offs,
                                                  const int* __restrict__ edata,
                                                  const float* __restrict__ bias,
                                                  f16* __restrict__ outh) {
    int wid  = threadIdx.x >> 6;
    int lane = threadIdx.x & 63;
    int node = blockIdx.x * 4 + wid;
    if (node >= NN) return;
    int q  = lane >> 4;
    int j8 = (lane & 15) * 8;
    int beg = offs[node], end = offs[node + 1];
    int nk = end - beg;
    float acc[8];
    #pragma unroll
    for (int u = 0; u < 8; ++u) acc[u] = 0.f;

    for (int k0 = 0; k0 < nk; k0 += 8) {
        int kA = k0 + q, kB = k0 + 4 + q;
        int sa = (kA < nk) ? edata[beg + kA] : 0;
        int sb = (kB < nk) ? edata[beg + kB] : 0;
        float wa = (kA < nk) ? 1.f : 0.f;
        float wb = (kB < nk) ? 1.f : 0.f;
        f16x8 va = *(const f16x8*)&hw[(size_t)sa * H + j8];
        f16x8 vb = *(const f16x8*)&hw[(size_t)sb * H + j8];
        #pragma unroll
        for (int u = 0; u < 8; ++u) acc[u] += wa * (float)va[u];
        #pragma unroll
        for (int u = 0; u < 8; ++u) acc[u] += wb * (float)vb[u];
    }
    // self term: hw'[node] (already dis-scaled)
    f16x8 hv = *(const f16x8*)&hw[(size_t)node * H + j8];
    if (q == 0) {
        #pragma unroll
        for (int u = 0; u < 8; ++u) acc[u] += (float)hv[u];
    }
    #pragma unroll
    for (int u = 0; u < 8; ++u) {
        acc[u] += __shfl_xor(acc[u], 16, 64);
        acc[u] += __shfl_xor(acc[u], 32, 64);
    }
    if (q == 0) {
        float dv = dis[node];
        f16x8 o;
        #pragma unroll
        for (int u = 0; u < 8; ++u) o[u] = (f16)fmaxf(dv * acc[u] + bias[j8 + u], 0.f);
        *(f16x8*)&outh[(size_t)node * H + j8] = o;
    }
}

// ---------------------------------------------------------------- mean-pool + linear head (2-way node-parallel)
__global__ __launch_bounds__(256) void pool_kernel(const f16* __restrict__ h,
                                                   const int* __restrict__ batch,
                                                   const float* __restrict__ linW,
                                                   const float* __restrict__ linb,
                                                   float* __restrict__ out) {
    __shared__ float pld[2][H];
    int g = blockIdx.x;
    int t = threadIdx.x;
    int f = t & 127, half = t >> 7;
    int lo = lower_bound_i(batch, NN, g);
    int hi = lower_bound_i(batch, NN, g + 1);
    float sum = 0.f;
    for (int n = lo + half; n < hi; n += 2) sum += (float)h[(size_t)n * H + f];
    pld[half][f] = sum;
    __syncthreads();
    if (t < H) {
        float cnt = (float)(hi - lo);
        pld[0][t] = (pld[0][t] + pld[1][t]) / fmaxf(cnt, 1.0f);
    }
    __syncthreads();
    if (t < NC) {
        float acc = linb[t];
        #pragma unroll 4
        for (int j = 0; j < H; ++j) acc += pld[0][j] * linW[j * NC + t];
        out[g * NC + t] = acc;
    }
}

// ---------------------------------------------------------------- launch
extern "C" void kernel_launch(void* const* d_in, const int* in_sizes, int n_in,
                              void* d_out, int out_size, void* d_ws, size_t ws_size,
                              hipStream_t stream) {
    const float* x     = (const float*)d_in[0];
    const int*   ei    = (const int*)d_in[1];
    const int*   batch = (const int*)d_in[2];
    const float* W0    = (const float*)d_in[3];
    const float* b0    = (const float*)d_in[4];
    const float* Ws    = (const float*)d_in[5];
    const float* bs    = (const float*)d_in[6];
    const float* linW  = (const float*)d_in[7];
    const float* linb  = (const float*)d_in[8];
    const int* src = ei;
    const int* dst = ei + NE;

    char* p = (char*)d_ws;
    auto alloc = [&](size_t bytes) -> void* {
        void* r = (void*)p;
        p += (bytes + 255) & ~(size_t)255;
        return r;
    };
    f16*   buf0   = (f16*)alloc((size_t)NN * H * 2);
    f16*   buf1   = (f16*)alloc((size_t)NN * H * 2);
    f16*   buf2   = (f16*)alloc((size_t)NN * H * 2);
    f16*   hwb    = (f16*)alloc((size_t)NN * H * 2);
    f16*   wt_hi  = (f16*)alloc((size_t)4 * H * H * 2);
    f16*   wt_lo  = (f16*)alloc((size_t)4 * H * H * 2);
    float* dis    = (float*)alloc((size_t)NN * 4);
    int*   deg    = (int*)alloc((size_t)NN * 4);
    int*   offs   = (int*)alloc((size_t)(NN + 1) * 4);
    int*   binned = (int*)alloc((size_t)NE * 4);
    int*   edata  = (int*)alloc((size_t)NE * 4);
    int*   psum   = (int*)alloc((size_t)SCAN_B * 4);
    int*   poff   = (int*)alloc((size_t)(SCAN_B + 1) * 4);
    int*   bcur   = (int*)alloc((size_t)NBUCK * 4);

    hipMemsetAsync(deg, 0, (size_t)NN * 4, stream);

    deg_kernel<<<(NE + 255) / 256, 256, 0, stream>>>(dst, deg);
    wprep_kernel<<<(4 * H * H) / 256, 256, 0, stream>>>(W0, Ws, wt_hi, wt_lo);
    scan1_kernel<<<SCAN_B, 256, 0, stream>>>(deg, psum);
    scan2_kernel<<<1, 64, 0, stream>>>(psum, poff, offs, bcur);
    scan3_kernel<<<SCAN_B, 256, 0, stream>>>(deg, poff, offs, dis);
    binA_kernel<<<(NE + CHUNK - 1) / CHUNK, 256, 0, stream>>>(src, dst, bcur, binned);
    binB_kernel<<<NBUCK, 256, 0, stream>>>(binned, poff, offs, edata);

    int gemm_grid = (NN + 255) / 256;
    int agg_grid  = (NN + 3) / 4;
    size_t WSZ = (size_t)H * H;

    gemm_kernel<1><<<gemm_grid, 512, 0, stream>>>(x, nullptr, wt_hi, wt_lo, dis, hwb);
    agg_kernel<<<agg_grid, 256, 0, stream>>>(hwb, dis, offs, edata, b0, buf0);
    gemm_kernel<0><<<gemm_grid, 512, 0, stream>>>(buf0, nullptr, wt_hi + WSZ, wt_lo + WSZ, dis, hwb);
    agg_kernel<<<agg_grid, 256, 0, stream>>>(hwb, dis, offs, edata, bs, buf1);
    gemm_kernel<0><<<gemm_grid, 512, 0, stream>>>(buf1, buf0, wt_hi + 2 * WSZ, wt_lo + 2 * WSZ, dis, hwb);
    agg_kernel<<<agg_grid, 256, 0, stream>>>(hwb, dis, offs, edata, bs + H, buf2);
    gemm_kernel<0><<<gemm_grid, 512, 0, stream>>>(buf2, buf1, wt_hi + 3 * WSZ, wt_lo + 3 * WSZ, dis, hwb);
    agg_kernel<<<agg_grid, 256, 0, stream>>>(hwb, dis, offs, edata, bs + 2 * H, buf0);

    pool_kernel<<<NG, 256, 0, stream>>>(buf0, batch, linW, linb, (float*)d_out);
}

// Round 9
// 442.650 us; speedup vs baseline: 1.4729x; 1.2103x over previous
//
#include <hip/hip_runtime.h>

#define NN 100000
#define NE 1600000
#define H  128
#define NG 512
#define NC 10
#define NBUCK  98     // ceil(NN/1024) dst buckets (dst>>10)
#define CHUNK  4096   // edges per pass-A block
#define EPAD   8192   // per-bucket padding slack in edata (1024 nodes * 8)

typedef _Float16 f16;
typedef __attribute__((ext_vector_type(8))) _Float16 f16x8;
typedef __attribute__((ext_vector_type(4))) _Float16 f16x4;
typedef __attribute__((ext_vector_type(4))) float    f32x4;

// ---------------------------------------------------------------- utilities
__device__ __forceinline__ int lower_bound_i(const int* __restrict__ a, int n, int val) {
    int lo = 0, hi = n;
    while (lo < hi) {
        int mid = (lo + hi) >> 1;
        if (a[mid] < val) lo = mid + 1; else hi = mid;
    }
    return lo;
}

// ---------------------------------------------------------------- coarse histogram (98 buckets)
__global__ __launch_bounds__(256) void histC_kernel(const int* __restrict__ dst,
                                                    int* __restrict__ hist0) {
    __shared__ int h[NBUCK];
    int t = threadIdx.x;
    if (t < NBUCK) h[t] = 0;
    __syncthreads();
    int e0 = blockIdx.x * CHUNK;
    #pragma unroll
    for (int i = 0; i < 16; ++i) {
        int e = e0 + i * 256 + t;
        if (e < NE) atomicAdd(&h[dst[e] >> 10], 1);
    }
    __syncthreads();
    if (t < NBUCK) atomicAdd(&hist0[t], h[t]);
}

// ---------------------------------------------------------------- bucket scan (tiny, 1 block)
__global__ void scan2_kernel(const int* __restrict__ hist0, int* __restrict__ poff,
                             int* __restrict__ bcur) {
    if (threadIdx.x == 0) {
        int run = 0;
        for (int b = 0; b < NBUCK; ++b) { poff[b] = run; bcur[b] = run; run += hist0[b]; }
        poff[NBUCK] = run;   // == NE
    }
}

// ---------------------------------------------------------------- pass A: bin edges by coarse bucket
// payload int: src (17b) | dstloc (10b) << 17
__global__ __launch_bounds__(256) void binA_kernel(const int* __restrict__ src,
                                                   const int* __restrict__ dst,
                                                   int* __restrict__ bcur,
                                                   int* __restrict__ binned) {
    __shared__ int hist[NBUCK];
    __shared__ int lbase[NBUCK];
    __shared__ int gbase[NBUCK];
    __shared__ int cur[NBUCK];
    __shared__ int stage[CHUNK];
    __shared__ int destp[CHUNK];
    int t  = threadIdx.x;
    int e0 = blockIdx.x * CHUNK;
    int cnt = NE - e0; if (cnt > CHUNK) cnt = CHUNK;

    if (t < NBUCK) hist[t] = 0;
    __syncthreads();

    int s_[16], d_[16];
    #pragma unroll
    for (int i = 0; i < 16; ++i) {
        int e = e0 + i * 256 + t;
        if (e < NE) {
            s_[i] = src[e]; d_[i] = dst[e];
            atomicAdd(&hist[d_[i] >> 10], 1);
        } else { s_[i] = -1; d_[i] = 0; }
    }
    __syncthreads();

    if (t < NBUCK) {
        int lb = 0;
        for (int i = 0; i < t; ++i) lb += hist[i];
        lbase[t] = lb;
        cur[t]   = lb;
        gbase[t] = atomicAdd(&bcur[t], hist[t]);
    }
    __syncthreads();

    #pragma unroll
    for (int i = 0; i < 16; ++i) {
        if (s_[i] >= 0) {
            int s = s_[i], d = d_[i];
            int b = d >> 10;
            int r = atomicAdd(&cur[b], 1);
            stage[r] = s | ((d & 1023) << 17);
            destp[r] = gbase[b] + (r - lbase[b]);
        }
    }
    __syncthreads();

    #pragma unroll
    for (int i = 0; i < 16; ++i) {
        int idx = i * 256 + t;
        if (idx < cnt) binned[destp[idx]] = stage[idx];
    }
}

// ---------------------------------------------------------------- pass B: fine hist + scan + dis + padded CSR placement
// 1024 threads, one node per thread. Node list: [self] + edges + pad(NN) to multiple of 8.
// offs_pk[d] = global_base | (len/8)<<22
__global__ __launch_bounds__(1024) void binB_kernel(const int* __restrict__ binned,
                                                    const int* __restrict__ poff,
                                                    int* __restrict__ edata,
                                                    int* __restrict__ offs_pk,
                                                    float* __restrict__ dis) {
    __shared__ int cnt[1024];
    __shared__ int cursor[1024];
    __shared__ int ws[16];
    int b = blockIdx.x, t = threadIdx.x;
    int lane = t & 63, wid = t >> 6;
    cnt[t] = 0;
    __syncthreads();
    int lo = poff[b], hi = poff[b + 1];
    for (int e = lo + t; e < hi; e += 1024) {
        atomicAdd(&cnt[(binned[e] >> 17) & 1023], 1);
    }
    __syncthreads();
    int gd = (b << 10) + t;
    int c = cnt[t];
    int L = (gd < NN) ? ((c + 8) & ~7) : 0;   // self + edges, rounded up to 8
    // block-wide exclusive scan of L
    int incl = L;
    #pragma unroll
    for (int d = 1; d < 64; d <<= 1) { int u = __shfl_up(incl, d, 64); if (lane >= d) incl += u; }
    if (lane == 63) ws[wid] = incl;
    __syncthreads();
    int wbase = 0;
    for (int w = 0; w < wid; ++w) wbase += ws[w];
    int lbase = wbase + incl - L;
    int epoff = poff[b] + b * EPAD;
    int gbase = epoff + lbase;
    if (gd < NN) {
        offs_pk[gd] = gbase | ((L >> 3) << 22);
        dis[gd] = rsqrtf((float)c + 1.0f);
        edata[gbase] = gd;                         // self entry
        for (int i = c + 1; i < L; ++i) edata[gbase + i] = NN;   // pads -> zero row
    }
    cursor[t] = lbase + 1;
    __syncthreads();
    for (int e = lo + t; e < hi; e += 1024) {
        int p = binned[e];
        int dloc = (p >> 17) & 1023;
        int r = atomicAdd(&cursor[dloc], 1);
        edata[epoff + r] = p & 0x1FFFF;
    }
}

// ---------------------------------------------------------------- W split prep: Wt_hi/Wt_lo [4][128][128] fp16, transposed
__global__ __launch_bounds__(256) void wprep_kernel(const float* __restrict__ W0,
                                                    const float* __restrict__ Ws,
                                                    f16* __restrict__ wt_hi,
                                                    f16* __restrict__ wt_lo) {
    int idx = blockIdx.x * 256 + threadIdx.x;   // 4*16384 total
    int m = idx >> 14;
    int k = (idx >> 7) & 127;
    int n = idx & 127;
    const float* Wm = (m == 0) ? W0 : (Ws + (size_t)(m - 1) * H * H);
    float v = Wm[k * H + n];
    f16 hi = (f16)v;
    float lo = v - (float)hi;
    wt_hi[(size_t)m * H * H + n * H + k] = hi;
    wt_lo[(size_t)m * H * H + n * H + k] = (f16)lo;
}

// ---------------------------------------------------------------- MFMA GEMM: hw' = fp16(dis * ((in0 [+ in1]) @ (W_hi + W_lo)))
// 512 threads = 8 waves; wave owns 32 rows; 256 rows/block. W staged in 64KB LDS
// (swizzled); A frags direct from global; swapped-operand MFMA -> direct 8B stores.
template <int FP32IN>
__global__ __launch_bounds__(512) void gemm_kernel(const void* __restrict__ in0,
                                                   const f16* __restrict__ in1,
                                                   const f16* __restrict__ wt_hi,
                                                   const f16* __restrict__ wt_lo,
                                                   const float* __restrict__ dis,
                                                   f16* __restrict__ hw) {
    __shared__ f16x8 sW[2][128 * 16];   // 64 KB, chunk-swizzled (c ^ (n&7))
    int t = threadIdx.x;
    int l = t & 63, w = t >> 6;
    int lr = l & 15, lq = l >> 4;
    int rowb = blockIdx.x * 256 + w * 32;

    const f16x8* wh = (const f16x8*)wt_hi;
    const f16x8* wl = (const f16x8*)wt_lo;
    #pragma unroll
    for (int i = 0; i < 4; ++i) {
        int ch = i * 512 + t;           // 0..2047
        int n = ch >> 4, c = ch & 15;
        int sw = n * 16 + (c ^ (n & 7));
        sW[0][sw] = wh[ch];
        sW[1][sw] = wl[ch];
    }

    f16x8 aF[2][4];
    #pragma unroll
    for (int rt = 0; rt < 2; ++rt) {
        int grow = rowb + rt * 16 + lr;
        if (grow >= NN) grow = NN - 1;
        #pragma unroll
        for (int ks = 0; ks < 4; ++ks) {
            int c = ks * 4 + lq;                 // k-chunk (16B) index 0..15
            f16x8 v;
            if (FP32IN) {
                const float* xp = (const float*)in0 + (size_t)grow * H + c * 8;
                f32x4 u0 = *(const f32x4*)xp;
                f32x4 u1 = *(const f32x4*)(xp + 4);
                #pragma unroll
                for (int u = 0; u < 4; ++u) { v[u] = (f16)u0[u]; v[u + 4] = (f16)u1[u]; }
            } else {
                v = *((const f16x8*)in0 + (size_t)grow * 16 + c);
                if (in1) {
                    f16x8 uu = *((const f16x8*)in1 + (size_t)grow * 16 + c);
                    v = v + uu;
                }
            }
            aF[rt][ks] = v;
        }
    }
    __syncthreads();

    f32x4 acc[2][8];
    #pragma unroll
    for (int rt = 0; rt < 2; ++rt)
        #pragma unroll
        for (int ct = 0; ct < 8; ++ct)
            acc[rt][ct] = (f32x4){0.f, 0.f, 0.f, 0.f};

    #pragma unroll
    for (int p = 0; p < 2; ++p) {
        #pragma unroll
        for (int ks = 0; ks < 4; ++ks) {
            int c = ks * 4 + lq;
            #pragma unroll
            for (int ct = 0; ct < 8; ++ct) {
                int n = ct * 16 + lr;
                f16x8 bF = sW[p][n * 16 + (c ^ (n & 7))];
                acc[0][ct] = __builtin_amdgcn_mfma_f32_16x16x32_f16(bF, aF[0][ks], acc[0][ct], 0, 0, 0);
                acc[1][ct] = __builtin_amdgcn_mfma_f32_16x16x32_f16(bF, aF[1][ks], acc[1][ct], 0, 0, 0);
            }
        }
    }

    // store hw' = dis * result: node = lane&15 of each tile; 4 regs = W-cols ct*16+lq*4..+3
    #pragma unroll
    for (int rt = 0; rt < 2; ++rt) {
        int grow = rowb + rt * 16 + lr;
        if (grow < NN) {
            float dv = dis[grow];
            #pragma unroll
            for (int ct = 0; ct < 8; ++ct) {
                f16x4 o;
                #pragma unroll
                for (int r = 0; r < 4; ++r) o[r] = (f16)(dv * acc[rt][ct][r]);
                *(f16x4*)&hw[(size_t)grow * H + ct * 16 + lq * 4] = o;
            }
        }
    }
}

// ---------------------------------------------------------------- aggregation (fp16 out)
// out[d] = relu(dis[d] * sum_slots hw'[slot] + bias); slots = [self]+edges+pads (uniform weight 1)
__global__ __launch_bounds__(256) void agg_kernel(const f16* __restrict__ hw,
                                                  const float* __restrict__ dis,
                                                  const int* __restrict__ offs_pk,
                                                  const int* __restrict__ edata,
                                                  const float* __restrict__ bias,
                                                  f16* __restrict__ outh) {
    int wid  = threadIdx.x >> 6;
    int lane = threadIdx.x & 63;
    int node = blockIdx.x * 4 + wid;
    if (node >= NN) return;
    int q  = lane >> 4;
    int j8 = (lane & 15) * 8;
    int w = offs_pk[node];
    int beg = w & 0x3FFFFF;
    int nit = (unsigned)w >> 22;
    float acc[8];
    #pragma unroll
    for (int u = 0; u < 8; ++u) acc[u] = 0.f;

    for (int it = 0; it < nit; ++it) {
        int base = beg + it * 8;
        int sa = edata[base + q];
        int sb = edata[base + 4 + q];
        f16x8 va = *(const f16x8*)&hw[(size_t)sa * H + j8];
        f16x8 vb = *(const f16x8*)&hw[(size_t)sb * H + j8];
        #pragma unroll
        for (int u = 0; u < 8; ++u) acc[u] += (float)va[u];
        #pragma unroll
        for (int u = 0; u < 8; ++u) acc[u] += (float)vb[u];
    }
    #pragma unroll
    for (int u = 0; u < 8; ++u) {
        acc[u] += __shfl_xor(acc[u], 16, 64);
        acc[u] += __shfl_xor(acc[u], 32, 64);
    }
    if (q == 0) {
        float dv = dis[node];
        f16x8 o;
        #pragma unroll
        for (int u = 0; u < 8; ++u) o[u] = (f16)fmaxf(dv * acc[u] + bias[j8 + u], 0.f);
        *(f16x8*)&outh[(size_t)node * H + j8] = o;
    }
}

// ---------------------------------------------------------------- mean-pool + linear head (2-way node-parallel)
__global__ __launch_bounds__(256) void pool_kernel(const f16* __restrict__ h,
                                                   const int* __restrict__ batch,
                                                   const float* __restrict__ linW,
                                                   const float* __restrict__ linb,
                                                   float* __restrict__ out) {
    __shared__ float pld[2][H];
    int g = blockIdx.x;
    int t = threadIdx.x;
    int f = t & 127, half = t >> 7;
    int lo = lower_bound_i(batch, NN, g);
    int hi = lower_bound_i(batch, NN, g + 1);
    float sum = 0.f;
    for (int n = lo + half; n < hi; n += 2) sum += (float)h[(size_t)n * H + f];
    pld[half][f] = sum;
    __syncthreads();
    if (t < H) {
        float cnt = (float)(hi - lo);
        pld[0][t] = (pld[0][t] + pld[1][t]) / fmaxf(cnt, 1.0f);
    }
    __syncthreads();
    if (t < NC) {
        float acc = linb[t];
        #pragma unroll 4
        for (int j = 0; j < H; ++j) acc += pld[0][j] * linW[j * NC + t];
        out[g * NC + t] = acc;
    }
}

// ---------------------------------------------------------------- launch
extern "C" void kernel_launch(void* const* d_in, const int* in_sizes, int n_in,
                              void* d_out, int out_size, void* d_ws, size_t ws_size,
                              hipStream_t stream) {
    const float* x     = (const float*)d_in[0];
    const int*   ei    = (const int*)d_in[1];
    const int*   batch = (const int*)d_in[2];
    const float* W0    = (const float*)d_in[3];
    const float* b0    = (const float*)d_in[4];
    const float* Ws    = (const float*)d_in[5];
    const float* bs    = (const float*)d_in[6];
    const float* linW  = (const float*)d_in[7];
    const float* linb  = (const float*)d_in[8];
    const int* src = ei;
    const int* dst = ei + NE;

    char* p = (char*)d_ws;
    auto alloc = [&](size_t bytes) -> void* {
        void* r = (void*)p;
        p += (bytes + 255) & ~(size_t)255;
        return r;
    };
    f16*   buf0    = (f16*)alloc((size_t)NN * H * 2);
    f16*   buf1    = (f16*)alloc((size_t)NN * H * 2);
    f16*   buf2    = (f16*)alloc((size_t)NN * H * 2);
    f16*   hwb     = (f16*)alloc((size_t)(NN + 1) * H * 2);   // row NN = zero row for pads
    f16*   wt_hi   = (f16*)alloc((size_t)4 * H * H * 2);
    f16*   wt_lo   = (f16*)alloc((size_t)4 * H * H * 2);
    float* dis     = (float*)alloc((size_t)NN * 4);
    int*   offs_pk = (int*)alloc((size_t)NN * 4);
    int*   binned  = (int*)alloc((size_t)NE * 4);
    int*   edata   = (int*)alloc((size_t)(NE + NBUCK * EPAD) * 4);
    int*   hist0   = (int*)alloc((size_t)NBUCK * 4);
    int*   poff    = (int*)alloc((size_t)(NBUCK + 1) * 4);
    int*   bcur    = (int*)alloc((size_t)NBUCK * 4);

    hipMemsetAsync(hist0, 0, (size_t)NBUCK * 4, stream);
    hipMemsetAsync(hwb + (size_t)NN * H, 0, (size_t)H * 2, stream);   // zero pad row

    wprep_kernel<<<(4 * H * H) / 256, 256, 0, stream>>>(W0, Ws, wt_hi, wt_lo);
    histC_kernel<<<(NE + CHUNK - 1) / CHUNK, 256, 0, stream>>>(dst, hist0);
    scan2_kernel<<<1, 64, 0, stream>>>(hist0, poff, bcur);
    binA_kernel<<<(NE + CHUNK - 1) / CHUNK, 256, 0, stream>>>(src, dst, bcur, binned);
    binB_kernel<<<NBUCK, 1024, 0, stream>>>(binned, poff, edata, offs_pk, dis);

    int gemm_grid = (NN + 255) / 256;
    int agg_grid  = (NN + 3) / 4;
    size_t WSZ = (size_t)H * H;

    gemm_kernel<1><<<gemm_grid, 512, 0, stream>>>(x, nullptr, wt_hi, wt_lo, dis, hwb);
    agg_kernel<<<agg_grid, 256, 0, stream>>>(hwb, dis, offs_pk, edata, b0, buf0);
    gemm_kernel<0><<<gemm_grid, 512, 0, stream>>>(buf0, nullptr, wt_hi + WSZ, wt_lo + WSZ, dis, hwb);
    agg_kernel<<<agg_grid, 256, 0, stream>>>(hwb, dis, offs_pk, edata, bs, buf1);
    gemm_kernel<0><<<gemm_grid, 512, 0, stream>>>(buf1, buf0, wt_hi + 2 * WSZ, wt_lo + 2 * WSZ, dis, hwb);
    agg_kernel<<<agg_grid, 256, 0, stream>>>(hwb, dis, offs_pk, edata, bs + H, buf2);
    gemm_kernel<0><<<gemm_grid, 512, 0, stream>>>(buf2, buf1, wt_hi + 3 * WSZ, wt_lo + 3 * WSZ, dis, hwb);
    agg_kernel<<<agg_grid, 256, 0, stream>>>(hwb, dis, offs_pk, edata, bs + 2 * H, buf0);

    pool_kernel<<<NG, 256, 0, stream>>>(buf0, batch, linW, linb, (float*)d_out);
}

// Round 10
// 409.623 us; speedup vs baseline: 1.5917x; 1.0806x over previous
//
#include <hip/hip_runtime.h>

#define NN 100000
#define NE 1600000
#define H  128
#define NG 512
#define NC 10
#define NBUCK  98       // ceil(NN/1024) dst buckets (dst>>10)
#define CHUNK  4096     // edges per pass-A block
#define BINCAP 18432    // per-bucket capacity in binned (mean 16384 + 16 sigma)
#define EDCAP  22528    // per-bucket capacity in edata (BINCAP + 4*1024 pad slack)

typedef _Float16 f16;
typedef __attribute__((ext_vector_type(8))) _Float16 f16x8;
typedef __attribute__((ext_vector_type(4))) _Float16 f16x4;
typedef __attribute__((ext_vector_type(4))) float    f32x4;

// ---------------------------------------------------------------- utilities
__device__ __forceinline__ int lower_bound_i(const int* __restrict__ a, int n, int val) {
    int lo = 0, hi = n;
    while (lo < hi) {
        int mid = (lo + hi) >> 1;
        if (a[mid] < val) lo = mid + 1; else hi = mid;
    }
    return lo;
}

// ---------------------------------------------------------------- pass A: bin edges by coarse bucket
// bucket b segment = binned[b*BINCAP ...]; payload int: src (17b) | dstloc (10b) << 17
__global__ __launch_bounds__(256) void binA_kernel(const int* __restrict__ src,
                                                   const int* __restrict__ dst,
                                                   int* __restrict__ bcur,
                                                   int* __restrict__ binned) {
    __shared__ int hist[NBUCK];
    __shared__ int lbase[NBUCK];
    __shared__ int gbase[NBUCK];
    __shared__ int cur[NBUCK];
    __shared__ int stage[CHUNK];
    __shared__ int destp[CHUNK];
    int t  = threadIdx.x;
    int e0 = blockIdx.x * CHUNK;
    int cnt = NE - e0; if (cnt > CHUNK) cnt = CHUNK;

    if (t < NBUCK) hist[t] = 0;
    __syncthreads();

    int s_[16], d_[16];
    #pragma unroll
    for (int i = 0; i < 16; ++i) {
        int e = e0 + i * 256 + t;
        if (e < NE) {
            s_[i] = src[e]; d_[i] = dst[e];
            atomicAdd(&hist[d_[i] >> 10], 1);
        } else { s_[i] = -1; d_[i] = 0; }
    }
    __syncthreads();

    if (t < NBUCK) {
        int lb = 0;
        for (int i = 0; i < t; ++i) lb += hist[i];
        lbase[t] = lb;
        cur[t]   = lb;
        gbase[t] = t * BINCAP + atomicAdd(&bcur[t], hist[t]);
    }
    __syncthreads();

    #pragma unroll
    for (int i = 0; i < 16; ++i) {
        if (s_[i] >= 0) {
            int s = s_[i], d = d_[i];
            int b = d >> 10;
            int r = atomicAdd(&cur[b], 1);
            stage[r] = s | ((d & 1023) << 17);
            destp[r] = gbase[b] + (r - lbase[b]);
        }
    }
    __syncthreads();

    #pragma unroll
    for (int i = 0; i < 16; ++i) {
        int idx = i * 256 + t;
        if (idx < cnt) binned[destp[idx]] = stage[idx];
    }
}

// ---------------------------------------------------------------- pass B: fine hist + scan + dis + padded CSR placement
// 1024 threads, one node per thread. Node list: [self] + edges + pad(NN) to multiple of 4.
// offs_pk[d] = global_base | (len/4)<<22
__global__ __launch_bounds__(1024) void binB_kernel(const int* __restrict__ binned,
                                                    const int* __restrict__ bcnt,
                                                    int* __restrict__ edata,
                                                    int* __restrict__ offs_pk,
                                                    float* __restrict__ dis) {
    __shared__ int cnt[1024];
    __shared__ int cursor[1024];
    __shared__ int ws[16];
    int b = blockIdx.x, t = threadIdx.x;
    int lane = t & 63, wid = t >> 6;
    cnt[t] = 0;
    __syncthreads();
    int lo = b * BINCAP, hi = lo + bcnt[b];
    for (int e = lo + t; e < hi; e += 1024) {
        atomicAdd(&cnt[(binned[e] >> 17) & 1023], 1);
    }
    __syncthreads();
    int gd = (b << 10) + t;
    int c = cnt[t];
    int L = (gd < NN) ? ((c + 4) & ~3) : 0;   // self + edges, rounded up to 4
    // block-wide exclusive scan of L
    int incl = L;
    #pragma unroll
    for (int d = 1; d < 64; d <<= 1) { int u = __shfl_up(incl, d, 64); if (lane >= d) incl += u; }
    if (lane == 63) ws[wid] = incl;
    __syncthreads();
    int wbase = 0;
    for (int w = 0; w < wid; ++w) wbase += ws[w];
    int lbase = wbase + incl - L;
    int epoff = b * EDCAP;
    int gbase = epoff + lbase;
    if (gd < NN) {
        offs_pk[gd] = gbase | ((L >> 2) << 22);
        dis[gd] = rsqrtf((float)c + 1.0f);
        edata[gbase] = gd;                                       // self entry
        for (int i = c + 1; i < L; ++i) edata[gbase + i] = NN;   // pads -> zero row
    }
    cursor[t] = lbase + 1;
    __syncthreads();
    for (int e = lo + t; e < hi; e += 1024) {
        int p = binned[e];
        int dloc = (p >> 17) & 1023;
        int r = atomicAdd(&cursor[dloc], 1);
        edata[epoff + r] = p & 0x1FFFF;
    }
}

// ---------------------------------------------------------------- W split prep: Wt_hi/Wt_lo [4][128][128] fp16, transposed
__global__ __launch_bounds__(256) void wprep_kernel(const float* __restrict__ W0,
                                                    const float* __restrict__ Ws,
                                                    f16* __restrict__ wt_hi,
                                                    f16* __restrict__ wt_lo) {
    int idx = blockIdx.x * 256 + threadIdx.x;   // 4*16384 total
    int m = idx >> 14;
    int k = (idx >> 7) & 127;
    int n = idx & 127;
    const float* Wm = (m == 0) ? W0 : (Ws + (size_t)(m - 1) * H * H);
    float v = Wm[k * H + n];
    f16 hi = (f16)v;
    float lo = v - (float)hi;
    wt_hi[(size_t)m * H * H + n * H + k] = hi;
    wt_lo[(size_t)m * H * H + n * H + k] = (f16)lo;
}

// ---------------------------------------------------------------- MFMA GEMM: hw' = fp16(dis * ((in0 [+ in1]) @ (W_hi + W_lo)))
// 512 threads = 8 waves; wave owns 32 rows; 256 rows/block. W staged in 64KB LDS
// (swizzled); A frags direct from global; swapped-operand MFMA -> direct 8B stores.
template <int FP32IN>
__global__ __launch_bounds__(512) void gemm_kernel(const void* __restrict__ in0,
                                                   const f16* __restrict__ in1,
                                                   const f16* __restrict__ wt_hi,
                                                   const f16* __restrict__ wt_lo,
                                                   const float* __restrict__ dis,
                                                   f16* __restrict__ hw) {
    __shared__ f16x8 sW[2][128 * 16];   // 64 KB, chunk-swizzled (c ^ (n&7))
    int t = threadIdx.x;
    int l = t & 63, w = t >> 6;
    int lr = l & 15, lq = l >> 4;
    int rowb = blockIdx.x * 256 + w * 32;

    const f16x8* wh = (const f16x8*)wt_hi;
    const f16x8* wl = (const f16x8*)wt_lo;
    #pragma unroll
    for (int i = 0; i < 4; ++i) {
        int ch = i * 512 + t;           // 0..2047
        int n = ch >> 4, c = ch & 15;
        int sw = n * 16 + (c ^ (n & 7));
        sW[0][sw] = wh[ch];
        sW[1][sw] = wl[ch];
    }

    f16x8 aF[2][4];
    #pragma unroll
    for (int rt = 0; rt < 2; ++rt) {
        int grow = rowb + rt * 16 + lr;
        if (grow >= NN) grow = NN - 1;
        #pragma unroll
        for (int ks = 0; ks < 4; ++ks) {
            int c = ks * 4 + lq;                 // k-chunk (16B) index 0..15
            f16x8 v;
            if (FP32IN) {
                const float* xp = (const float*)in0 + (size_t)grow * H + c * 8;
                f32x4 u0 = *(const f32x4*)xp;
                f32x4 u1 = *(const f32x4*)(xp + 4);
                #pragma unroll
                for (int u = 0; u < 4; ++u) { v[u] = (f16)u0[u]; v[u + 4] = (f16)u1[u]; }
            } else {
                v = *((const f16x8*)in0 + (size_t)grow * 16 + c);
                if (in1) {
                    f16x8 uu = *((const f16x8*)in1 + (size_t)grow * 16 + c);
                    v = v + uu;
                }
            }
            aF[rt][ks] = v;
        }
    }
    __syncthreads();

    f32x4 acc[2][8];
    #pragma unroll
    for (int rt = 0; rt < 2; ++rt)
        #pragma unroll
        for (int ct = 0; ct < 8; ++ct)
            acc[rt][ct] = (f32x4){0.f, 0.f, 0.f, 0.f};

    #pragma unroll
    for (int p = 0; p < 2; ++p) {
        #pragma unroll
        for (int ks = 0; ks < 4; ++ks) {
            int c = ks * 4 + lq;
            #pragma unroll
            for (int ct = 0; ct < 8; ++ct) {
                int n = ct * 16 + lr;
                f16x8 bF = sW[p][n * 16 + (c ^ (n & 7))];
                acc[0][ct] = __builtin_amdgcn_mfma_f32_16x16x32_f16(bF, aF[0][ks], acc[0][ct], 0, 0, 0);
                acc[1][ct] = __builtin_amdgcn_mfma_f32_16x16x32_f16(bF, aF[1][ks], acc[1][ct], 0, 0, 0);
            }
        }
    }

    // store hw' = dis * result: node = lane&15 of each tile; 4 regs = W-cols ct*16+lq*4..+3
    #pragma unroll
    for (int rt = 0; rt < 2; ++rt) {
        int grow = rowb + rt * 16 + lr;
        if (grow < NN) {
            float dv = dis[grow];
            #pragma unroll
            for (int ct = 0; ct < 8; ++ct) {
                f16x4 o;
                #pragma unroll
                for (int r = 0; r < 4; ++r) o[r] = (f16)(dv * acc[rt][ct][r]);
                *(f16x4*)&hw[(size_t)grow * H + ct * 16 + lq * 4] = o;
            }
        }
    }
}

// ---------------------------------------------------------------- aggregation (fp16 out)
// out[d] = relu(dis[d] * sum_slots hw'[slot] + bias); slots = [self]+edges+pads, pad-to-4
// loop: nit4>>1 double-gather iterations + optional single-gather tail (uniform per wave)
__global__ __launch_bounds__(256) void agg_kernel(const f16* __restrict__ hw,
                                                  const float* __restrict__ dis,
                                                  const int* __restrict__ offs_pk,
                                                  const int* __restrict__ edata,
                                                  const float* __restrict__ bias,
                                                  f16* __restrict__ outh) {
    int wid  = threadIdx.x >> 6;
    int lane = threadIdx.x & 63;
    int node = blockIdx.x * 4 + wid;
    if (node >= NN) return;
    int q  = lane >> 4;
    int j8 = (lane & 15) * 8;
    int w = offs_pk[node];
    int beg = w & 0x3FFFFF;
    int nit4 = (unsigned)w >> 22;
    int nit8 = nit4 >> 1;
    float acc[8];
    #pragma unroll
    for (int u = 0; u < 8; ++u) acc[u] = 0.f;

    for (int it = 0; it < nit8; ++it) {
        int base = beg + it * 8;
        int sa = edata[base + q];
        int sb = edata[base + 4 + q];
        f16x8 va = *(const f16x8*)&hw[(size_t)sa * H + j8];
        f16x8 vb = *(const f16x8*)&hw[(size_t)sb * H + j8];
        f16x8 vs = va + vb;                       // v_pk_add_f16 x4
        #pragma unroll
        for (int u = 0; u < 8; ++u) acc[u] += (float)vs[u];
    }
    if (nit4 & 1) {
        int base = beg + nit8 * 8;
        int sa = edata[base + q];
        f16x8 va = *(const f16x8*)&hw[(size_t)sa * H + j8];
        #pragma unroll
        for (int u = 0; u < 8; ++u) acc[u] += (float)va[u];
    }
    #pragma unroll
    for (int u = 0; u < 8; ++u) {
        acc[u] += __shfl_xor(acc[u], 16, 64);
        acc[u] += __shfl_xor(acc[u], 32, 64);
    }
    if (q == 0) {
        float dv = dis[node];
        f16x8 o;
        #pragma unroll
        for (int u = 0; u < 8; ++u) o[u] = (f16)fmaxf(dv * acc[u] + bias[j8 + u], 0.f);
        *(f16x8*)&outh[(size_t)node * H + j8] = o;
    }
}

// ---------------------------------------------------------------- mean-pool + linear head (4-way node-parallel)
__global__ __launch_bounds__(512) void pool_kernel(const f16* __restrict__ h,
                                                   const int* __restrict__ batch,
                                                   const float* __restrict__ linW,
                                                   const float* __restrict__ linb,
                                                   float* __restrict__ out) {
    __shared__ float pld[4][H];
    int g = blockIdx.x;
    int t = threadIdx.x;
    int f = t & 127, quad = t >> 7;
    int lo = lower_bound_i(batch, NN, g);
    int hi = lower_bound_i(batch, NN, g + 1);
    float sum = 0.f;
    for (int n = lo + quad; n < hi; n += 4) sum += (float)h[(size_t)n * H + f];
    pld[quad][f] = sum;
    __syncthreads();
    if (t < H) {
        float cnt = (float)(hi - lo);
        pld[0][t] = (pld[0][t] + pld[1][t] + pld[2][t] + pld[3][t]) / fmaxf(cnt, 1.0f);
    }
    __syncthreads();
    if (t < NC) {
        float acc = linb[t];
        #pragma unroll 4
        for (int j = 0; j < H; ++j) acc += pld[0][j] * linW[j * NC + t];
        out[g * NC + t] = acc;
    }
}

// ---------------------------------------------------------------- launch
extern "C" void kernel_launch(void* const* d_in, const int* in_sizes, int n_in,
                              void* d_out, int out_size, void* d_ws, size_t ws_size,
                              hipStream_t stream) {
    const float* x     = (const float*)d_in[0];
    const int*   ei    = (const int*)d_in[1];
    const int*   batch = (const int*)d_in[2];
    const float* W0    = (const float*)d_in[3];
    const float* b0    = (const float*)d_in[4];
    const float* Ws    = (const float*)d_in[5];
    const float* bs    = (const float*)d_in[6];
    const float* linW  = (const float*)d_in[7];
    const float* linb  = (const float*)d_in[8];
    const int* src = ei;
    const int* dst = ei + NE;

    char* p = (char*)d_ws;
    auto alloc = [&](size_t bytes) -> void* {
        void* r = (void*)p;
        p += (bytes + 255) & ~(size_t)255;
        return r;
    };
    f16*   buf0    = (f16*)alloc((size_t)NN * H * 2);
    f16*   buf1    = (f16*)alloc((size_t)NN * H * 2);
    f16*   buf2    = (f16*)alloc((size_t)NN * H * 2);
    f16*   hwb     = (f16*)alloc((size_t)(NN + 1) * H * 2);   // row NN = zero row for pads
    f16*   wt_hi   = (f16*)alloc((size_t)4 * H * H * 2);
    f16*   wt_lo   = (f16*)alloc((size_t)4 * H * H * 2);
    float* dis     = (float*)alloc((size_t)NN * 4);
    int*   offs_pk = (int*)alloc((size_t)NN * 4);
    int*   binned  = (int*)alloc((size_t)NBUCK * BINCAP * 4);
    int*   edata   = (int*)alloc((size_t)NBUCK * EDCAP * 4);
    int*   bcur    = (int*)alloc((size_t)NBUCK * 4);

    hipMemsetAsync(bcur, 0, (size_t)NBUCK * 4, stream);
    hipMemsetAsync(hwb + (size_t)NN * H, 0, (size_t)H * 2, stream);   // zero pad row

    wprep_kernel<<<(4 * H * H) / 256, 256, 0, stream>>>(W0, Ws, wt_hi, wt_lo);
    binA_kernel<<<(NE + CHUNK - 1) / CHUNK, 256, 0, stream>>>(src, dst, bcur, binned);
    binB_kernel<<<NBUCK, 1024, 0, stream>>>(binned, bcur, edata, offs_pk, dis);

    int gemm_grid = (NN + 255) / 256;
    int agg_grid  = (NN + 3) / 4;
    size_t WSZ = (size_t)H * H;

    gemm_kernel<1><<<gemm_grid, 512, 0, stream>>>(x, nullptr, wt_hi, wt_lo, dis, hwb);
    agg_kernel<<<agg_grid, 256, 0, stream>>>(hwb, dis, offs_pk, edata, b0, buf0);
    gemm_kernel<0><<<gemm_grid, 512, 0, stream>>>(buf0, nullptr, wt_hi + WSZ, wt_lo + WSZ, dis, hwb);
    agg_kernel<<<agg_grid, 256, 0, stream>>>(hwb, dis, offs_pk, edata, bs, buf1);
    gemm_kernel<0><<<gemm_grid, 512, 0, stream>>>(buf1, buf0, wt_hi + 2 * WSZ, wt_lo + 2 * WSZ, dis, hwb);
    agg_kernel<<<agg_grid, 256, 0, stream>>>(hwb, dis, offs_pk, edata, bs + H, buf2);
    gemm_kernel<0><<<gemm_grid, 512, 0, stream>>>(buf2, buf1, wt_hi + 3 * WSZ, wt_lo + 3 * WSZ, dis, hwb);
    agg_kernel<<<agg_grid, 256, 0, stream>>>(hwb, dis, offs_pk, edata, bs + 2 * H, buf0);

    pool_kernel<<<NG, 512, 0, stream>>>(buf0, batch, linW, linb, (float*)d_out);
}

// Round 11
// 396.799 us; speedup vs baseline: 1.6431x; 1.0323x over previous
//
#include <hip/hip_runtime.h>

#define NN 100000
#define NE 1600000
#define H  128
#define NG 512
#define NC 10
#define NBUCK  98       // ceil(NN/1024) dst buckets (dst>>10)
#define CHUNK  4096     // edges per pass-A block
#define BINCAP 18432    // per-bucket capacity in binned (mean 16384 + 16 sigma)
#define EDCAP  26624    // per-bucket capacity in edata (BINCAP + 8*1024 pad slack)

typedef _Float16 f16;
typedef __attribute__((ext_vector_type(8))) _Float16 f16x8;
typedef __attribute__((ext_vector_type(4))) _Float16 f16x4;
typedef __attribute__((ext_vector_type(4))) float    f32x4;

// ---------------------------------------------------------------- utilities
__device__ __forceinline__ int lower_bound_i(const int* __restrict__ a, int n, int val) {
    int lo = 0, hi = n;
    while (lo < hi) {
        int mid = (lo + hi) >> 1;
        if (a[mid] < val) lo = mid + 1; else hi = mid;
    }
    return lo;
}

// ---------------------------------------------------------------- W split prep + init (folds old memsets)
__global__ __launch_bounds__(256) void wprep_kernel(const float* __restrict__ W0,
                                                    const float* __restrict__ Ws,
                                                    f16* __restrict__ wt_hi,
                                                    f16* __restrict__ wt_lo,
                                                    int* __restrict__ bcur,
                                                    f16* __restrict__ hwb) {
    int t = threadIdx.x;
    if (blockIdx.x == 0) {
        if (t < NBUCK) bcur[t] = 0;
        if (t >= 128 && t < 192) ((int*)(hwb + (size_t)NN * H))[t - 128] = 0;  // zero pad row
    }
    int idx = blockIdx.x * 256 + t;             // 4*16384 total
    int m = idx >> 14;
    int k = (idx >> 7) & 127;
    int n = idx & 127;
    const float* Wm = (m == 0) ? W0 : (Ws + (size_t)(m - 1) * H * H);
    float v = Wm[k * H + n];
    f16 hi = (f16)v;
    float lo = v - (float)hi;
    wt_hi[(size_t)m * H * H + n * H + k] = hi;
    wt_lo[(size_t)m * H * H + n * H + k] = (f16)lo;
}

// ---------------------------------------------------------------- pass A: bin edges by coarse bucket
// bucket b segment = binned[b*BINCAP ...]; payload int: src (17b) | dstloc (10b) << 17
__global__ __launch_bounds__(256) void binA_kernel(const int* __restrict__ src,
                                                   const int* __restrict__ dst,
                                                   int* __restrict__ bcur,
                                                   int* __restrict__ binned) {
    __shared__ int hist[NBUCK];
    __shared__ int lbase[NBUCK];
    __shared__ int gbase[NBUCK];
    __shared__ int cur[NBUCK];
    __shared__ int stage[CHUNK];
    __shared__ int destp[CHUNK];
    int t  = threadIdx.x;
    int e0 = blockIdx.x * CHUNK;
    int cnt = NE - e0; if (cnt > CHUNK) cnt = CHUNK;

    if (t < NBUCK) hist[t] = 0;
    __syncthreads();

    int s_[16], d_[16];
    #pragma unroll
    for (int i = 0; i < 16; ++i) {
        int e = e0 + i * 256 + t;
        if (e < NE) {
            s_[i] = src[e]; d_[i] = dst[e];
            atomicAdd(&hist[d_[i] >> 10], 1);
        } else { s_[i] = -1; d_[i] = 0; }
    }
    __syncthreads();

    if (t < NBUCK) {
        int lb = 0;
        for (int i = 0; i < t; ++i) lb += hist[i];
        lbase[t] = lb;
        cur[t]   = lb;
        gbase[t] = t * BINCAP + atomicAdd(&bcur[t], hist[t]);
    }
    __syncthreads();

    #pragma unroll
    for (int i = 0; i < 16; ++i) {
        if (s_[i] >= 0) {
            int s = s_[i], d = d_[i];
            int b = d >> 10;
            int r = atomicAdd(&cur[b], 1);
            stage[r] = s | ((d & 1023) << 17);
            destp[r] = gbase[b] + (r - lbase[b]);
        }
    }
    __syncthreads();

    #pragma unroll
    for (int i = 0; i < 16; ++i) {
        int idx = i * 256 + t;
        if (idx < cnt) binned[destp[idx]] = stage[idx];
    }
}

// ---------------------------------------------------------------- pass B: fine hist + scan + dis + padded CSR placement
// 1024 threads, one node per thread. Node list: [self] + edges + pad(NN) to multiple of 8.
// offs_pk[d] = global_base | (len/8)<<22
__global__ __launch_bounds__(1024) void binB_kernel(const int* __restrict__ binned,
                                                    const int* __restrict__ bcnt,
                                                    int* __restrict__ edata,
                                                    int* __restrict__ offs_pk,
                                                    float* __restrict__ dis) {
    __shared__ int cnt[1024];
    __shared__ int cursor[1024];
    __shared__ int ws[16];
    int b = blockIdx.x, t = threadIdx.x;
    int lane = t & 63, wid = t >> 6;
    cnt[t] = 0;
    __syncthreads();
    int lo = b * BINCAP, hi = lo + bcnt[b];
    for (int e = lo + t; e < hi; e += 1024) {
        atomicAdd(&cnt[(binned[e] >> 17) & 1023], 1);
    }
    __syncthreads();
    int gd = (b << 10) + t;
    int c = cnt[t];
    int L = (gd < NN) ? ((c + 8) & ~7) : 0;   // self + edges, rounded up to 8
    // block-wide exclusive scan of L
    int incl = L;
    #pragma unroll
    for (int d = 1; d < 64; d <<= 1) { int u = __shfl_up(incl, d, 64); if (lane >= d) incl += u; }
    if (lane == 63) ws[wid] = incl;
    __syncthreads();
    int wbase = 0;
    for (int w = 0; w < wid; ++w) wbase += ws[w];
    int lbase = wbase + incl - L;
    int epoff = b * EDCAP;
    int gbase = epoff + lbase;
    if (gd < NN) {
        offs_pk[gd] = gbase | ((L >> 3) << 22);
        dis[gd] = rsqrtf((float)c + 1.0f);
        edata[gbase] = gd;                                       // self entry
        for (int i = c + 1; i < L; ++i) edata[gbase + i] = NN;   // pads -> zero row
    }
    cursor[t] = lbase + 1;
    __syncthreads();
    for (int e = lo + t; e < hi; e += 1024) {
        int p = binned[e];
        int dloc = (p >> 17) & 1023;
        int r = atomicAdd(&cursor[dloc], 1);
        edata[epoff + r] = p & 0x1FFFF;
    }
}

// ---------------------------------------------------------------- MFMA GEMM: hw' = fp16(dis * ((in0 [+ in1]) @ (W_hi + W_lo)))
// 512 threads = 8 waves; wave owns 32 rows; 256 rows/block. W staged in 64KB LDS
// (swizzled); A frags direct from global; swapped-operand MFMA -> direct 8B stores.
template <int FP32IN>
__global__ __launch_bounds__(512) void gemm_kernel(const void* __restrict__ in0,
                                                   const f16* __restrict__ in1,
                                                   const f16* __restrict__ wt_hi,
                                                   const f16* __restrict__ wt_lo,
                                                   const float* __restrict__ dis,
                                                   f16* __restrict__ hw) {
    __shared__ f16x8 sW[2][128 * 16];   // 64 KB, chunk-swizzled (c ^ (n&7))
    int t = threadIdx.x;
    int l = t & 63, w = t >> 6;
    int lr = l & 15, lq = l >> 4;
    int rowb = blockIdx.x * 256 + w * 32;

    const f16x8* wh = (const f16x8*)wt_hi;
    const f16x8* wl = (const f16x8*)wt_lo;
    #pragma unroll
    for (int i = 0; i < 4; ++i) {
        int ch = i * 512 + t;           // 0..2047
        int n = ch >> 4, c = ch & 15;
        int sw = n * 16 + (c ^ (n & 7));
        sW[0][sw] = wh[ch];
        sW[1][sw] = wl[ch];
    }

    f16x8 aF[2][4];
    #pragma unroll
    for (int rt = 0; rt < 2; ++rt) {
        int grow = rowb + rt * 16 + lr;
        if (grow >= NN) grow = NN - 1;
        #pragma unroll
        for (int ks = 0; ks < 4; ++ks) {
            int c = ks * 4 + lq;                 // k-chunk (16B) index 0..15
            f16x8 v;
            if (FP32IN) {
                const float* xp = (const float*)in0 + (size_t)grow * H + c * 8;
                f32x4 u0 = *(const f32x4*)xp;
                f32x4 u1 = *(const f32x4*)(xp + 4);
                #pragma unroll
                for (int u = 0; u < 4; ++u) { v[u] = (f16)u0[u]; v[u + 4] = (f16)u1[u]; }
            } else {
                v = *((const f16x8*)in0 + (size_t)grow * 16 + c);
                if (in1) {
                    f16x8 uu = *((const f16x8*)in1 + (size_t)grow * 16 + c);
                    v = v + uu;
                }
            }
            aF[rt][ks] = v;
        }
    }
    __syncthreads();

    f32x4 acc[2][8];
    #pragma unroll
    for (int rt = 0; rt < 2; ++rt)
        #pragma unroll
        for (int ct = 0; ct < 8; ++ct)
            acc[rt][ct] = (f32x4){0.f, 0.f, 0.f, 0.f};

    #pragma unroll
    for (int p = 0; p < 2; ++p) {
        #pragma unroll
        for (int ks = 0; ks < 4; ++ks) {
            int c = ks * 4 + lq;
            #pragma unroll
            for (int ct = 0; ct < 8; ++ct) {
                int n = ct * 16 + lr;
                f16x8 bF = sW[p][n * 16 + (c ^ (n & 7))];
                acc[0][ct] = __builtin_amdgcn_mfma_f32_16x16x32_f16(bF, aF[0][ks], acc[0][ct], 0, 0, 0);
                acc[1][ct] = __builtin_amdgcn_mfma_f32_16x16x32_f16(bF, aF[1][ks], acc[1][ct], 0, 0, 0);
            }
        }
    }

    // store hw' = dis * result: node = lane&15 of each tile; 4 regs = W-cols ct*16+lq*4..+3
    #pragma unroll
    for (int rt = 0; rt < 2; ++rt) {
        int grow = rowb + rt * 16 + lr;
        if (grow < NN) {
            float dv = dis[grow];
            #pragma unroll
            for (int ct = 0; ct < 8; ++ct) {
                f16x4 o;
                #pragma unroll
                for (int r = 0; r < 4; ++r) o[r] = (f16)(dv * acc[rt][ct][r]);
                *(f16x4*)&hw[(size_t)grow * H + ct * 16 + lq * 4] = o;
            }
        }
    }
}

// ---------------------------------------------------------------- aggregation (fp16 out)
// out[d] = relu(dis[d] * sum_slots hw'[slot] + bias); slots = [self]+edges+pads, pad-to-8
// main loop: 16 slots/iter (4 independent gathers in flight) + optional 8-slot tail.
// In-iteration f16 tree-add (pk_add), cross-iteration f32 accumulate.
__global__ __launch_bounds__(256) void agg_kernel(const f16* __restrict__ hw,
                                                  const float* __restrict__ dis,
                                                  const int* __restrict__ offs_pk,
                                                  const int* __restrict__ edata,
                                                  const float* __restrict__ bias,
                                                  f16* __restrict__ outh) {
    int wid  = threadIdx.x >> 6;
    int lane = threadIdx.x & 63;
    int node = blockIdx.x * 4 + wid;
    if (node >= NN) return;
    int q  = lane >> 4;
    int j8 = (lane & 15) * 8;
    int w = offs_pk[node];
    int beg = w & 0x3FFFFF;
    int nit8 = (unsigned)w >> 22;
    float acc[8];
    #pragma unroll
    for (int u = 0; u < 8; ++u) acc[u] = 0.f;

    int it = 0;
    for (; it + 2 <= nit8; it += 2) {
        int base = beg + it * 8;
        int s0 = edata[base + q];
        int s1 = edata[base + 4 + q];
        int s2 = edata[base + 8 + q];
        int s3 = edata[base + 12 + q];
        f16x8 v0 = *(const f16x8*)&hw[(size_t)s0 * H + j8];
        f16x8 v1 = *(const f16x8*)&hw[(size_t)s1 * H + j8];
        f16x8 v2 = *(const f16x8*)&hw[(size_t)s2 * H + j8];
        f16x8 v3 = *(const f16x8*)&hw[(size_t)s3 * H + j8];
        f16x8 vt = (v0 + v1) + (v2 + v3);         // v_pk_add_f16 tree
        #pragma unroll
        for (int u = 0; u < 8; ++u) acc[u] += (float)vt[u];
    }
    if (it < nit8) {
        int base = beg + it * 8;
        int s0 = edata[base + q];
        int s1 = edata[base + 4 + q];
        f16x8 v0 = *(const f16x8*)&hw[(size_t)s0 * H + j8];
        f16x8 v1 = *(const f16x8*)&hw[(size_t)s1 * H + j8];
        f16x8 vt = v0 + v1;
        #pragma unroll
        for (int u = 0; u < 8; ++u) acc[u] += (float)vt[u];
    }
    #pragma unroll
    for (int u = 0; u < 8; ++u) {
        acc[u] += __shfl_xor(acc[u], 16, 64);
        acc[u] += __shfl_xor(acc[u], 32, 64);
    }
    if (q == 0) {
        float dv = dis[node];
        f16x8 o;
        #pragma unroll
        for (int u = 0; u < 8; ++u) o[u] = (f16)fmaxf(dv * acc[u] + bias[j8 + u], 0.f);
        *(f16x8*)&outh[(size_t)node * H + j8] = o;
    }
}

// ---------------------------------------------------------------- mean-pool + linear head (4-way node-parallel)
__global__ __launch_bounds__(512) void pool_kernel(const f16* __restrict__ h,
                                                   const int* __restrict__ batch,
                                                   const float* __restrict__ linW,
                                                   const float* __restrict__ linb,
                                                   float* __restrict__ out) {
    __shared__ float pld[4][H];
    int g = blockIdx.x;
    int t = threadIdx.x;
    int f = t & 127, quad = t >> 7;
    int lo = lower_bound_i(batch, NN, g);
    int hi = lower_bound_i(batch, NN, g + 1);
    float sum = 0.f;
    for (int n = lo + quad; n < hi; n += 4) sum += (float)h[(size_t)n * H + f];
    pld[quad][f] = sum;
    __syncthreads();
    if (t < H) {
        float cnt = (float)(hi - lo);
        pld[0][t] = (pld[0][t] + pld[1][t] + pld[2][t] + pld[3][t]) / fmaxf(cnt, 1.0f);
    }
    __syncthreads();
    if (t < NC) {
        float acc = linb[t];
        #pragma unroll 4
        for (int j = 0; j < H; ++j) acc += pld[0][j] * linW[j * NC + t];
        out[g * NC + t] = acc;
    }
}

// ---------------------------------------------------------------- launch
extern "C" void kernel_launch(void* const* d_in, const int* in_sizes, int n_in,
                              void* d_out, int out_size, void* d_ws, size_t ws_size,
                              hipStream_t stream) {
    const float* x     = (const float*)d_in[0];
    const int*   ei    = (const int*)d_in[1];
    const int*   batch = (const int*)d_in[2];
    const float* W0    = (const float*)d_in[3];
    const float* b0    = (const float*)d_in[4];
    const float* Ws    = (const float*)d_in[5];
    const float* bs    = (const float*)d_in[6];
    const float* linW  = (const float*)d_in[7];
    const float* linb  = (const float*)d_in[8];
    const int* src = ei;
    const int* dst = ei + NE;

    char* p = (char*)d_ws;
    auto alloc = [&](size_t bytes) -> void* {
        void* r = (void*)p;
        p += (bytes + 255) & ~(size_t)255;
        return r;
    };
    f16*   buf0    = (f16*)alloc((size_t)NN * H * 2);
    f16*   buf1    = (f16*)alloc((size_t)NN * H * 2);
    f16*   buf2    = (f16*)alloc((size_t)NN * H * 2);
    f16*   hwb     = (f16*)alloc((size_t)(NN + 1) * H * 2);   // row NN = zero row for pads
    f16*   wt_hi   = (f16*)alloc((size_t)4 * H * H * 2);
    f16*   wt_lo   = (f16*)alloc((size_t)4 * H * H * 2);
    float* dis     = (float*)alloc((size_t)NN * 4);
    int*   offs_pk = (int*)alloc((size_t)NN * 4);
    int*   binned  = (int*)alloc((size_t)NBUCK * BINCAP * 4);
    int*   edata   = (int*)alloc((size_t)NBUCK * EDCAP * 4);
    int*   bcur    = (int*)alloc((size_t)NBUCK * 4);

    wprep_kernel<<<(4 * H * H) / 256, 256, 0, stream>>>(W0, Ws, wt_hi, wt_lo, bcur, hwb);
    binA_kernel<<<(NE + CHUNK - 1) / CHUNK, 256, 0, stream>>>(src, dst, bcur, binned);
    binB_kernel<<<NBUCK, 1024, 0, stream>>>(binned, bcur, edata, offs_pk, dis);

    int gemm_grid = (NN + 255) / 256;
    int agg_grid  = (NN + 3) / 4;
    size_t WSZ = (size_t)H * H;

    gemm_kernel<1><<<gemm_grid, 512, 0, stream>>>(x, nullptr, wt_hi, wt_lo, dis, hwb);
    agg_kernel<<<agg_grid, 256, 0, stream>>>(hwb, dis, offs_pk, edata, b0, buf0);
    gemm_kernel<0><<<gemm_grid, 512, 0, stream>>>(buf0, nullptr, wt_hi + WSZ, wt_lo + WSZ, dis, hwb);
    agg_kernel<<<agg_grid, 256, 0, stream>>>(hwb, dis, offs_pk, edata, bs, buf1);
    gemm_kernel<0><<<gemm_grid, 512, 0, stream>>>(buf1, buf0, wt_hi + 2 * WSZ, wt_lo + 2 * WSZ, dis, hwb);
    agg_kernel<<<agg_grid, 256, 0, stream>>>(hwb, dis, offs_pk, edata, bs + H, buf2);
    gemm_kernel<0><<<gemm_grid, 512, 0, stream>>>(buf2, buf1, wt_hi + 3 * WSZ, wt_lo + 3 * WSZ, dis, hwb);
    agg_kernel<<<agg_grid, 256, 0, stream>>>(hwb, dis, offs_pk, edata, bs + 2 * H, buf0);

    pool_kernel<<<NG, 512, 0, stream>>>(buf0, batch, linW, linb, (float*)d_out);
}